// Round 3
// baseline (7606.992 us; speedup 1.0000x reference)
//
#include <hip/hip_runtime.h>
#include <hip/hip_bf16.h>

#define BB 8
#define TT 512
#define KK 8
#define HH 128
#define G3 384
#define DIN 100
#define DG 50
#define NL 20

#if __has_builtin(__builtin_amdgcn_rcpf)
#define RCP_(x) __builtin_amdgcn_rcpf(x)
#else
#define RCP_(x) (1.0f/(x))
#endif

__device__ __forceinline__ float fexp_(float x) { return __expf(x); }
__device__ __forceinline__ float fsig_(float x) { return RCP_(1.0f + __expf(-x)); }
__device__ __forceinline__ float ftanh_(float x) {
    float e = __expf(2.0f * x);          // saturates correctly: inf -> 1, 0 -> -1
    return 1.0f - 2.0f * RCP_(e + 1.0f);
}
// LDS-ordering barrier that does NOT drain vmcnt (prefetches stay in flight)
__device__ __forceinline__ void barrier_() {
    asm volatile("s_waitcnt lgkmcnt(0)\n\ts_barrier" ::: "memory");
}

// ---------------- kernel 1a: g3x = x @ W_ih^T + b_lstm ; alphax = x @ Wa_ih^T + b_alpha
__global__ __launch_bounds__(512, 1)
void embed_gates_kernel(const int* __restrict__ wid, const int* __restrict__ bwid,
                        const float* __restrict__ wtab, const float* __restrict__ bwtab,
                        const float* __restrict__ Wih, const float* __restrict__ Waih,
                        const float* __restrict__ bl, const float* __restrict__ ba,
                        float* __restrict__ g3x, float* __restrict__ axo,
                        int c0, int CH)
{
    __shared__ float xs[8][104];
    const int tid = threadIdx.x;
    const int bpg = CH >> 3;
    const int b = blockIdx.x / bpg;
    const int tg = blockIdx.x % bpg;
    const int t0 = c0 + tg * 8;

    for (int idx = tid; idx < 800; idx += 512) {
        int tt = idx / 100;
        int c = idx - tt * 100;
        int t = t0 + tt;
        float v;
        if (c < 50) v = wtab[(long)wid[b * TT + t] * 50 + c];
        else        v = bwtab[(long)bwid[b * TT + t] * 50 + (c - 50)];
        xs[tt][c] = v;
    }
    __syncthreads();

    const int row = tid;
    float w[100];
    const float* wr;
    float bias;
    if (row < G3) { wr = Wih + (long)row * DIN; bias = bl[row]; }
    else          { wr = Waih + (long)(row - G3) * DIN; bias = ba[row - G3]; }
    const float4* wr4 = (const float4*)wr;
#pragma unroll
    for (int q = 0; q < 25; ++q) {
        float4 v = wr4[q];
        w[4*q] = v.x; w[4*q+1] = v.y; w[4*q+2] = v.z; w[4*q+3] = v.w;
    }
#pragma unroll 1
    for (int tt = 0; tt < 8; ++tt) {
        float a = bias;
#pragma unroll
        for (int c = 0; c < 100; ++c) a += w[c] * xs[tt][c];
        int lt = t0 - c0 + tt;
        if (row < G3) g3x[((long)b * CH + lt) * G3 + row] = a;
        else          axo[((long)b * CH + lt) * HH + (row - G3)] = a;
    }
}

// ---------------- kernel 1b: gwT[b][t][384][8] = Ww_ih @ gaz_emb + b_word
__global__ __launch_bounds__(384, 1)
void gaz_gates_kernel(const int* __restrict__ gids, const float* __restrict__ gtab,
                      const float* __restrict__ Wwih, const float* __restrict__ bw,
                      float* __restrict__ gwT, int c0, int CH)
{
    __shared__ float ges[64][52];
    const int tid = threadIdx.x;
    const int bpg = CH >> 3;
    const int b = blockIdx.x / bpg;
    const int tg = blockIdx.x % bpg;
    const int t0 = c0 + tg * 8;

    for (int idx = tid; idx < 64 * 50; idx += 384) {
        int p = idx / 50;
        int c = idx - p * 50;
        int tt = p >> 3, k = p & 7;
        int gid = gids[((long)(b * TT + t0 + tt)) * KK + k];
        ges[p][c] = gtab[(long)gid * DG + c];
    }
    __syncthreads();

    const int row = tid;
    float w[50];
    const float2* wr2 = (const float2*)(Wwih + (long)row * DG);
#pragma unroll
    for (int q = 0; q < 25; ++q) { float2 v = wr2[q]; w[2*q] = v.x; w[2*q+1] = v.y; }
    const float bias = bw[row];
    const int lt0 = t0 - c0;
#pragma unroll 1
    for (int p = 0; p < 64; ++p) {
        float a = bias;
#pragma unroll
        for (int c = 0; c < 50; ++c) a += w[c] * ges[p][c];
        int tt = p >> 3, k = p & 7;
        gwT[(((long)b * CH + lt0 + tt) * G3 + row) * KK + k] = a;
    }
}

// ---------------- kernel 2: sequential lattice scan, one block per batch
// NOTE: Whh/Wwhh intentionally NOT __restrict__: prevents LICM from hoisting
// 192 loop-invariant weight loads into registers (would spill to scratch).
__global__ __launch_bounds__(512, 2)
void lattice_scan_kernel(const float* __restrict__ g3x, const float* __restrict__ axb,
                         const float* __restrict__ gwT, const int* __restrict__ gstarts,
                         const int* __restrict__ gmask,
                         const float* Whh, const float* Wwhh,
                         const float* __restrict__ Wahh,
                         float* hs, float* state,
                         int c0, int CH)
{
    __shared__ float cring[8][132];
    __shared__ float cwS[8][132];
    __shared__ float wwh[8][388];
    __shared__ float whh[G3];
    __shared__ float hcur[HH];

    const int tid = threadIdx.x;
    const int b = blockIdx.x;
    const int ce = tid & 3;        // quad column-slice (phases C/E)
    const int rq = tid >> 2;       // 0..127  output row (phases C/D/E)
    const int kB = tid & 7;        // phase B gaz index
    const int r2 = tid >> 3;       // 0..63   phase B row base

    // register-resident Wa_hh quarter-row (rotated col layout)
    float WA[32];
    {
        const float* arow = Wahh + (long)rq * HH;
#pragma unroll
        for (int g = 0; g < 8; ++g) {
            int off = 32 * ce + ((4 * g + 8 * ce) & 31);
            float4 v = *(const float4*)(arow + off);
            WA[4*g] = v.x; WA[4*g+1] = v.y; WA[4*g+2] = v.z; WA[4*g+3] = v.w;
        }
    }

    float* st = state + (long)b * 4480;  // cring 1024 | wwh 3072 | whh 384
    if (c0 == 0) {
        for (int idx = tid; idx < 8 * 132; idx += 512) ((float*)cring)[idx] = 0.f;
        for (int idx = tid; idx < 8 * 388; idx += 512) ((float*)wwh)[idx] = 0.f;
        for (int idx = tid; idx < G3; idx += 512) whh[idx] = 0.f;
    } else {
        for (int idx = tid; idx < 1024; idx += 512) cring[idx >> 7][idx & 127] = st[idx];
        for (int idx = tid; idx < 3072; idx += 512) wwh[idx / 384][idx % 384] = st[1024 + idx];
        for (int idx = tid; idx < 384; idx += 512) whh[idx] = st[4096 + idx];
    }
    barrier_();

    const long g3base = (long)b * CH * G3;
    const long axbase = (long)b * CH * HH;
    const long gwbase = (long)b * CH * 3072;

    // ---- prefetch registers for step c0
    float rg0 = g3x[g3base + rq];
    float rg1 = g3x[g3base + rq + 128];
    float rg2 = g3x[g3base + rq + 256];
    float rax = axb[axbase + rq];
    float rgw[6];
    int rs, rm;
    {
        const float* gw = gwT + gwbase;
#pragma unroll
        for (int u = 0; u < 2; ++u) {
            int rr = r2 + 64 * u;
            rgw[u*3+0] = gw[(rr)       * KK + kB];
            rgw[u*3+1] = gw[(rr + 128) * KK + kB];
            rgw[u*3+2] = gw[(rr + 256) * KK + kB];
        }
        rs = gstarts[(b * TT + c0) * KK + kB];
        rm = gmask[(b * TT + c0) * KK + kB];
    }

    for (int j = c0; j < c0 + CH; ++j) {
        const int lt = j - c0;

        // ---- capture step-j operands
        const bool valid = (rm != 0);
        const unsigned mask8 = (unsigned)(__ballot(valid) & 0xffull);
        const bool hw_any = (mask8 != 0u);
        const int slot = rs & 7;
        const float t0_ = rgw[0], t1_ = rgw[1], t2_ = rgw[2];
        const float t3_ = rgw[3], t4_ = rgw[4], t5_ = rgw[5];
        const float cg0 = rg0, cg1 = rg1, cg2 = rg2, cax = rax;

        // ---- issue prefetch for step j+1 (floats across raw barriers)
        if (lt + 1 < CH) {
            const int l2 = lt + 1;
            rg0 = g3x[g3base + (long)l2 * G3 + rq];
            rg1 = g3x[g3base + (long)l2 * G3 + rq + 128];
            rg2 = g3x[g3base + (long)l2 * G3 + rq + 256];
            rax = axb[axbase + (long)l2 * HH + rq];
            const float* gw = gwT + gwbase + (long)l2 * 3072;
#pragma unroll
            for (int u = 0; u < 2; ++u) {
                int rr = r2 + 64 * u;
                rgw[u*3+0] = gw[(rr)       * KK + kB];
                rgw[u*3+1] = gw[(rr + 128) * KK + kB];
                rgw[u*3+2] = gw[(rr + 256) * KK + kB];
            }
            rs = gstarts[(b * TT + j + 1) * KK + kB];
            rm = gmask[(b * TT + j + 1) * KK + kB];
        }

        // ---- Phase B: word-LSTM cells, unconditional (masked k zeroed in C)
        {
            float iw = t0_ + wwh[slot][r2];
            float fw = t1_ + wwh[slot][r2 + 128];
            float gv = t2_ + wwh[slot][r2 + 256];
            float cs = cring[slot][r2];
            cwS[kB][r2] = fsig_(fw) * cs + fsig_(iw) * ftanh_(gv);
            int rr = r2 + 64;
            iw = t3_ + wwh[slot][rr];
            fw = t4_ + wwh[slot][rr + 128];
            gv = t5_ + wwh[slot][rr + 256];
            cs = cring[slot][rr];
            cwS[kB][rr] = fsig_(fw) * cs + fsig_(iw) * ftanh_(gv);
        }
        barrier_();

        // ---- Phase C: alpha aggregation, wave-uniform skip per k
        float sumw = 0.f, sumwc = 0.f;
#pragma unroll
        for (int k = 0; k < 8; ++k) {
            if (mask8 & (1u << k)) {
                float acc = 0.f;
#pragma unroll
                for (int g = 0; g < 8; ++g) {
                    int off = 32 * ce + ((4 * g + 8 * ce) & 31);
                    const float* p = &cwS[k][off];
                    acc += WA[4*g] * p[0] + WA[4*g+1] * p[1] + WA[4*g+2] * p[2] + WA[4*g+3] * p[3];
                }
                acc += __shfl_xor(acc, 1);
                acc += __shfl_xor(acc, 2);
                float a = fsig_(cax + acc);
                float w = fexp_(a);
                sumw += w;
                sumwc += w * cwS[k][rq];
            }
        }

        // ---- Phase D: char cell + merge
        float i_ = fsig_(cg0 + whh[rq]);
        float o_ = fsig_(cg1 + whh[rq + 128]);
        float g_ = ftanh_(cg2 + whh[rq + 256]);
        float cprev = cring[(j - 1) & 7][rq];
        float wc = fexp_(i_);
        float csoft = (wc * g_ + sumwc) / (wc + sumw);
        float ccpl = (1.f - i_) * cprev + i_ * g_;
        float cn = hw_any ? csoft : ccpl;
        float hn = o_ * ftanh_(cn);
        if (ce == 0) {
            cring[j & 7][rq] = cn;
            hcur[rq] = hn;
            hs[((long)b * CH + lt) * HH + rq] = hn;
        }
        barrier_();

        // ---- Phase E: W_hh@h and Ww_hh@h, weights streamed from L2 each step
        float accE[6] = {0.f, 0.f, 0.f, 0.f, 0.f, 0.f};
#pragma unroll
        for (int g = 0; g < 8; ++g) {
            int off = 32 * ce + ((4 * g + 8 * ce) & 31);
            const float4 hv = *(const float4*)&hcur[off];
#pragma unroll
            for (int i = 0; i < 3; ++i) {
                const float4 wv = *(const float4*)(Whh + (long)(rq + 128 * i) * HH + off);
                accE[i] += wv.x * hv.x + wv.y * hv.y + wv.z * hv.z + wv.w * hv.w;
            }
#pragma unroll
            for (int i = 0; i < 3; ++i) {
                const float4 wv = *(const float4*)(Wwhh + (long)(rq + 128 * i) * HH + off);
                accE[3 + i] += wv.x * hv.x + wv.y * hv.y + wv.z * hv.z + wv.w * hv.w;
            }
        }
#pragma unroll
        for (int i = 0; i < 6; ++i) {
            float a = accE[i];
            a += __shfl_xor(a, 1);
            a += __shfl_xor(a, 2);
            if (ce == 0) {
                if (i < 3) whh[rq + 128 * i] = a;
                else       wwh[j & 7][rq + 128 * (i - 3)] = a;
            }
        }
        barrier_();
    }

    // persist state for next chunk
    for (int idx = tid; idx < 1024; idx += 512) st[idx] = cring[idx >> 7][idx & 127];
    for (int idx = tid; idx < 3072; idx += 512) st[1024 + idx] = wwh[idx / 384][idx % 384];
    for (int idx = tid; idx < 384; idx += 512) st[4096 + idx] = whh[idx];
}

// ---------------- kernel 3: logits + argmax (fwd==bwd, so fold W_tag halves)
__global__ __launch_bounds__(320, 1)
void tag_kernel(const float* __restrict__ hs, const float* __restrict__ Wtag,
                const float* __restrict__ btag, const int* __restrict__ maskp,
                int* __restrict__ out, int c0, int CH)
{
    __shared__ float ht[16][132];
    __shared__ float lg[16][20];
    const int tid = threadIdx.x;
    const int bpg = CH >> 4;
    const int b = blockIdx.x / bpg;
    const int tg = blockIdx.x % bpg;
    const int lt0 = tg * 16;

    for (int idx = tid; idx < 16 * 128; idx += 320)
        ht[idx >> 7][idx & 127] = hs[((long)b * CH + lt0 + (idx >> 7)) * HH + (idx & 127)];
    __syncthreads();

    {
        int tl = tid / 20, l = tid - tl * 20;
        float a = btag[l];
        const float* w0 = Wtag + (long)l * 256;
#pragma unroll
        for (int r = 0; r < 128; ++r) a += (w0[r] + w0[r + 128]) * ht[tl][r];
        lg[tl][l] = a;
    }
    __syncthreads();
    if (tid < 16) {
        float best = lg[tid][0];
        int bi = 0;
#pragma unroll
        for (int l = 1; l < NL; ++l) {
            float v = lg[tid][l];
            if (v > best) { best = v; bi = l; }   // first-max (np.argmax semantics)
        }
        int t = c0 + lt0 + tid;
        out[b * TT + t] = maskp[b * TT + t] * bi;
    }
}

extern "C" void kernel_launch(void* const* d_in, const int* in_sizes, int n_in,
                              void* d_out, int out_size, void* d_ws, size_t ws_size,
                              hipStream_t stream) {
    const int* word_inputs   = (const int*)d_in[0];
    const int* biword_inputs = (const int*)d_in[1];
    const int* gaz_word_ids  = (const int*)d_in[2];
    const int* gaz_starts    = (const int*)d_in[3];
    const int* gaz_mask      = (const int*)d_in[4];
    const int* maskp         = (const int*)d_in[5];
    const float* word_table   = (const float*)d_in[6];
    const float* biword_table = (const float*)d_in[7];
    const float* gaz_table    = (const float*)d_in[8];
    const float* W_ih   = (const float*)d_in[9];
    const float* W_hh   = (const float*)d_in[10];
    const float* b_lstm = (const float*)d_in[11];
    const float* Wa_ih  = (const float*)d_in[12];
    const float* Wa_hh  = (const float*)d_in[13];
    const float* b_alpha= (const float*)d_in[14];
    const float* Ww_ih  = (const float*)d_in[15];
    const float* Ww_hh  = (const float*)d_in[16];
    const float* b_word = (const float*)d_in[17];
    const float* W_tag  = (const float*)d_in[18];
    const float* b_tag  = (const float*)d_in[19];
    int* out = (int*)d_out;
    float* ws = (float*)d_ws;

    // choose T-chunk so workspace fits: bytes = 118784*CH + 143360
    int CH = 16;
    if      (ws_size >= 118784UL * 512 + 143360UL) CH = 512;
    else if (ws_size >= 118784UL * 128 + 143360UL) CH = 128;
    else if (ws_size >= 118784UL *  32 + 143360UL) CH = 32;

    float* g3x = ws;                               // B*CH*384
    float* axb = g3x + 8L * CH * 384;              // B*CH*128
    float* gwT = axb + 8L * CH * 128;              // B*CH*384*8
    float* hsb = gwT + 8L * CH * 3072;             // B*CH*128
    float* stb = hsb + 8L * CH * 128;              // B*4480

    for (int c0 = 0; c0 < TT; c0 += CH) {
        embed_gates_kernel<<<CH, 512, 0, stream>>>(word_inputs, biword_inputs,
                                                   word_table, biword_table,
                                                   W_ih, Wa_ih, b_lstm, b_alpha,
                                                   g3x, axb, c0, CH);
        gaz_gates_kernel<<<CH, 384, 0, stream>>>(gaz_word_ids, gaz_table,
                                                 Ww_ih, b_word, gwT, c0, CH);
        lattice_scan_kernel<<<BB, 512, 0, stream>>>(g3x, axb, gwT, gaz_starts, gaz_mask,
                                                    W_hh, Ww_hh, Wa_hh, hsb, stb, c0, CH);
        tag_kernel<<<CH / 2, 320, 0, stream>>>(hsb, W_tag, b_tag, maskp, out, c0, CH);
    }
}

// Round 4
// 3697.633 us; speedup vs baseline: 2.0573x; 2.0573x over previous
//
#include <hip/hip_runtime.h>
#include <hip/hip_bf16.h>

#define BB 8
#define TT 512
#define KK 8
#define HH 128
#define G3 384
#define DIN 100
#define DG 50
#define NL 20

#if __has_builtin(__builtin_amdgcn_rcpf)
#define RCP_(x) __builtin_amdgcn_rcpf(x)
#else
#define RCP_(x) (1.0f/(x))
#endif

__device__ __forceinline__ float fexp_(float x) { return __expf(x); }
__device__ __forceinline__ float fsig_(float x) { return RCP_(1.0f + __expf(-x)); }
__device__ __forceinline__ float ftanh_(float x) {
    float e = __expf(2.0f * x);          // saturates correctly: inf -> 1, 0 -> -1
    return 1.0f - 2.0f * RCP_(e + 1.0f);
}
// LDS-ordering barrier that does NOT drain vmcnt (prefetches stay in flight)
__device__ __forceinline__ void barrier_() {
    asm volatile("s_waitcnt lgkmcnt(0)\n\ts_barrier" ::: "memory");
}

// ---------------- kernel 1a: g3x = x @ W_ih^T + b_lstm ; alphax = x @ Wa_ih^T + b_alpha
__global__ __launch_bounds__(512, 1)
void embed_gates_kernel(const int* __restrict__ wid, const int* __restrict__ bwid,
                        const float* __restrict__ wtab, const float* __restrict__ bwtab,
                        const float* __restrict__ Wih, const float* __restrict__ Waih,
                        const float* __restrict__ bl, const float* __restrict__ ba,
                        float* __restrict__ g3x, float* __restrict__ axo,
                        int c0, int CH)
{
    __shared__ float xs[8][104];
    const int tid = threadIdx.x;
    const int bpg = CH >> 3;
    const int b = blockIdx.x / bpg;
    const int tg = blockIdx.x % bpg;
    const int t0 = c0 + tg * 8;

    for (int idx = tid; idx < 800; idx += 512) {
        int tt = idx / 100;
        int c = idx - tt * 100;
        int t = t0 + tt;
        float v;
        if (c < 50) v = wtab[(long)wid[b * TT + t] * 50 + c];
        else        v = bwtab[(long)bwid[b * TT + t] * 50 + (c - 50)];
        xs[tt][c] = v;
    }
    __syncthreads();

    const int row = tid;
    float w[100];
    const float* wr;
    float bias;
    if (row < G3) { wr = Wih + (long)row * DIN; bias = bl[row]; }
    else          { wr = Waih + (long)(row - G3) * DIN; bias = ba[row - G3]; }
    const float4* wr4 = (const float4*)wr;
#pragma unroll
    for (int q = 0; q < 25; ++q) {
        float4 v = wr4[q];
        w[4*q] = v.x; w[4*q+1] = v.y; w[4*q+2] = v.z; w[4*q+3] = v.w;
    }
#pragma unroll 1
    for (int tt = 0; tt < 8; ++tt) {
        float a = bias;
#pragma unroll
        for (int c = 0; c < 100; ++c) a += w[c] * xs[tt][c];
        int lt = t0 - c0 + tt;
        if (row < G3) g3x[((long)b * CH + lt) * G3 + row] = a;
        else          axo[((long)b * CH + lt) * HH + (row - G3)] = a;
    }
}

// ---------------- kernel 1b: gwT[b][t][k][384] = Ww_ih @ gaz_emb + b_word
__global__ __launch_bounds__(384, 1)
void gaz_gates_kernel(const int* __restrict__ gids, const float* __restrict__ gtab,
                      const float* __restrict__ Wwih, const float* __restrict__ bw,
                      float* __restrict__ gwT, int c0, int CH)
{
    __shared__ float ges[64][52];
    const int tid = threadIdx.x;
    const int bpg = CH >> 3;
    const int b = blockIdx.x / bpg;
    const int tg = blockIdx.x % bpg;
    const int t0 = c0 + tg * 8;

    for (int idx = tid; idx < 64 * 50; idx += 384) {
        int p = idx / 50;
        int c = idx - p * 50;
        int tt = p >> 3, k = p & 7;
        int gid = gids[((long)(b * TT + t0 + tt)) * KK + k];
        ges[p][c] = gtab[(long)gid * DG + c];
    }
    __syncthreads();

    const int row = tid;
    float w[50];
    const float2* wr2 = (const float2*)(Wwih + (long)row * DG);
#pragma unroll
    for (int q = 0; q < 25; ++q) { float2 v = wr2[q]; w[2*q] = v.x; w[2*q+1] = v.y; }
    const float bias = bw[row];
    const int lt0 = t0 - c0;
#pragma unroll 1
    for (int p = 0; p < 64; ++p) {
        float a = bias;
#pragma unroll
        for (int c = 0; c < 50; ++c) a += w[c] * ges[p][c];
        int tt = p >> 3, k = p & 7;
        gwT[((long)(b * CH + lt0 + tt) * KK + k) * G3 + row] = a;
    }
}

// ---------------- kernel 2: sequential lattice scan, one block per batch
// 256 threads = 4 waves = 1 wave/SIMD -> 512 regs/lane available.
// Full weight residency: W2 = [W_hh;Ww_hh] 3 rows/thread (384 regs) + Wa half-row (64).
__global__ __launch_bounds__(256, 1)
void lattice_scan_kernel(const float* __restrict__ g3x, const float* __restrict__ axb,
                         const float* __restrict__ gwT, const int* __restrict__ gstarts,
                         const int* __restrict__ gmask,
                         const float* __restrict__ Whh, const float* __restrict__ Wwhh,
                         const float* __restrict__ Wahh,
                         float* __restrict__ hs, float* __restrict__ state,
                         int c0, int CH)
{
    __shared__ float cring[8][132];
    __shared__ float cwS[8][132];
    __shared__ float wwh[8][388];
    __shared__ float whh[G3];
    __shared__ float hcur[HH];

    const int t = threadIdx.x;
    const int b = blockIdx.x;
    const int rq = t >> 1, hf = t & 1;     // phase C/D mapping
    const int kB = t & 7, rb = (t >> 3) << 2;  // phase B mapping: k, 4-row base

    // ---- register weight stash (448 floats/thread)
    float W0[HH], W1[HH], W2r[HH], WAr[64];
    {
        const float4* r0p = (const float4*)(Whh + (long)t * HH);
        const float4* r1p = (t < 128) ? (const float4*)(Whh + (long)(t + 256) * HH)
                                      : (const float4*)(Wwhh + (long)(t - 128) * HH);
        const float4* r2p = (const float4*)(Wwhh + (long)(t + 128) * HH);
#pragma unroll
        for (int q = 0; q < 32; ++q) {
            float4 v0 = r0p[q]; W0[4*q]=v0.x; W0[4*q+1]=v0.y; W0[4*q+2]=v0.z; W0[4*q+3]=v0.w;
            float4 v1 = r1p[q]; W1[4*q]=v1.x; W1[4*q+1]=v1.y; W1[4*q+2]=v1.z; W1[4*q+3]=v1.w;
            float4 v2 = r2p[q]; W2r[4*q]=v2.x; W2r[4*q+1]=v2.y; W2r[4*q+2]=v2.z; W2r[4*q+3]=v2.w;
        }
        const float4* wap = (const float4*)(Wahh + (long)rq * HH + hf * 64);
#pragma unroll
        for (int q = 0; q < 16; ++q) {
            float4 v = wap[q]; WAr[4*q]=v.x; WAr[4*q+1]=v.y; WAr[4*q+2]=v.z; WAr[4*q+3]=v.w;
        }
    }

    float* st = state + (long)b * 4480;  // cring 1024 | wwh 3072 | whh 384
    if (c0 == 0) {
        for (int idx = t; idx < 8 * 132; idx += 256) ((float*)cring)[idx] = 0.f;
        for (int idx = t; idx < 8 * 388; idx += 256) ((float*)wwh)[idx] = 0.f;
        for (int idx = t; idx < G3; idx += 256) whh[idx] = 0.f;
    } else {
        for (int idx = t; idx < 1024; idx += 256) cring[idx >> 7][idx & 127] = st[idx];
        for (int idx = t; idx < 3072; idx += 256) wwh[idx / 384][idx % 384] = st[1024 + idx];
        for (int idx = t; idx < 384; idx += 256) whh[idx] = st[4096 + idx];
    }
    barrier_();

    const long gwstep = (long)KK * G3;        // 3072
    const float* gwB = gwT + (long)b * CH * gwstep + (long)kB * G3;
    const long g3base = (long)b * CH * G3;
    const long axbase = (long)b * CH * HH;

    // ---- prefetch (step c0): gaz gate float4s + start/mask
    float4 pA, pF, pG; int rs, rm;
    {
        const float* gw = gwB;
        pA = *(const float4*)(gw + rb);
        pF = *(const float4*)(gw + rb + 128);
        pG = *(const float4*)(gw + rb + 256);
        rs = gstarts[(b * TT + c0) * KK + kB];
        rm = gmask  [(b * TT + c0) * KK + kB];
    }

    for (int j = c0; j < c0 + CH; ++j) {
        const int lt = j - c0;
        const bool valid = (rm != 0);
        const unsigned mask8 = (unsigned)(__ballot(valid) & 0xffull);
        const bool hw_any = (mask8 != 0u);
        const int slot = rs & 7;
        const float4 cAx = pA, cFx = pF, cGx = pG;

        // prefetch next step's gaz gates (latency crosses the raw barriers)
        if (lt + 1 < CH) {
            const float* gw = gwB + (long)(lt + 1) * gwstep;
            pA = *(const float4*)(gw + rb);
            pF = *(const float4*)(gw + rb + 128);
            pG = *(const float4*)(gw + rb + 256);
            rs = gstarts[(b * TT + j + 1) * KK + kB];
            rm = gmask  [(b * TT + j + 1) * KK + kB];
        }
        // this step's char-gate inputs (consumed 2 phases later)
        const float dg0 = g3x[g3base + (long)lt * G3 + rq];
        const float dg1 = g3x[g3base + (long)lt * G3 + rq + 128];
        const float dg2 = g3x[g3base + (long)lt * G3 + rq + 256];
        const float dax = axb[axbase + (long)lt * HH + rq];

        // ---- Phase B: word-LSTM cells (4 rows for gaz entry kB)
        {
            float4 wi = *(const float4*)&wwh[slot][rb];
            float4 wf = *(const float4*)&wwh[slot][rb + 128];
            float4 wg = *(const float4*)&wwh[slot][rb + 256];
            float4 cs = *(const float4*)&cring[slot][rb];
            float4 cw;
            cw.x = fsig_(cFx.x + wf.x) * cs.x + fsig_(cAx.x + wi.x) * ftanh_(cGx.x + wg.x);
            cw.y = fsig_(cFx.y + wf.y) * cs.y + fsig_(cAx.y + wi.y) * ftanh_(cGx.y + wg.y);
            cw.z = fsig_(cFx.z + wf.z) * cs.z + fsig_(cAx.z + wi.z) * ftanh_(cGx.z + wg.z);
            cw.w = fsig_(cFx.w + wf.w) * cs.w + fsig_(cAx.w + wi.w) * ftanh_(cGx.w + wg.w);
            *(float4*)&cwS[kB][rb] = cw;
        }
        barrier_();

        // ---- Phase C: alpha aggregation; thread owns (row rq, col-half hf)
        float sumw = 0.f, sumwc = 0.f;
#pragma unroll
        for (int k = 0; k < 8; ++k) {
            if (mask8 & (1u << k)) {
                float acc = 0.f;
                const float* cp = &cwS[k][hf * 64];
#pragma unroll
                for (int q = 0; q < 16; ++q) {
                    float4 cv = *(const float4*)(cp + 4 * q);
                    acc += WAr[4*q]*cv.x + WAr[4*q+1]*cv.y + WAr[4*q+2]*cv.z + WAr[4*q+3]*cv.w;
                }
                acc += __shfl_xor(acc, 1);     // pair-combine halves
                float a = fsig_(dax + acc);
                float w = fexp_(a);
                sumw += w;
                sumwc += w * cwS[k][rq];
            }
        }

        // ---- Phase D: char cell + merge (both lanes compute, hf==0 writes)
        float i_ = fsig_(dg0 + whh[rq]);
        float o_ = fsig_(dg1 + whh[rq + 128]);
        float g_ = ftanh_(dg2 + whh[rq + 256]);
        float cprev = cring[(j - 1) & 7][rq];
        float wc = fexp_(i_);
        float csoft = (wc * g_ + sumwc) / (wc + sumw);
        float ccpl = (1.f - i_) * cprev + i_ * g_;
        float cn = hw_any ? csoft : ccpl;
        float hn = o_ * ftanh_(cn);
        if (hf == 0) {
            cring[j & 7][rq] = cn;
            hcur[rq] = hn;
            hs[((long)b * CH + lt) * HH + rq] = hn;
        }
        barrier_();

        // ---- Phase E: 3 full 128-dots per thread from the register stash
        float a0=0.f, a1=0.f, a2=0.f, b0=0.f, b1=0.f, b2=0.f;
#pragma unroll
        for (int q = 0; q < 16; ++q) {
            float4 h0 = *(const float4*)&hcur[8 * q];
            float4 h1 = *(const float4*)&hcur[8 * q + 4];
            a0 += W0[8*q]*h0.x + W0[8*q+1]*h0.y + W0[8*q+2]*h0.z + W0[8*q+3]*h0.w;
            b0 += W0[8*q+4]*h1.x + W0[8*q+5]*h1.y + W0[8*q+6]*h1.z + W0[8*q+7]*h1.w;
            a1 += W1[8*q]*h0.x + W1[8*q+1]*h0.y + W1[8*q+2]*h0.z + W1[8*q+3]*h0.w;
            b1 += W1[8*q+4]*h1.x + W1[8*q+5]*h1.y + W1[8*q+6]*h1.z + W1[8*q+7]*h1.w;
            a2 += W2r[8*q]*h0.x + W2r[8*q+1]*h0.y + W2r[8*q+2]*h0.z + W2r[8*q+3]*h0.w;
            b2 += W2r[8*q+4]*h1.x + W2r[8*q+5]*h1.y + W2r[8*q+6]*h1.z + W2r[8*q+7]*h1.w;
        }
        {
            float e0 = a0 + b0, e1 = a1 + b1, e2 = a2 + b2;
            whh[t] = e0;                                   // row t (< 256): W_hh part
            if (t < 128) whh[t + 256] = e1;                // rows 256..383
            else         wwh[j & 7][t - 128] = e1;         // Ww rows 0..127
            wwh[j & 7][t + 128] = e2;                      // Ww rows 128..383
        }
        barrier_();
    }

    // persist state for next chunk
    for (int idx = t; idx < 1024; idx += 256) st[idx] = cring[idx >> 7][idx & 127];
    for (int idx = t; idx < 3072; idx += 256) st[1024 + idx] = wwh[idx / 384][idx % 384];
    for (int idx = t; idx < 384; idx += 256) st[4096 + idx] = whh[idx];
}

// ---------------- kernel 3: logits + argmax (fwd==bwd, so fold W_tag halves)
__global__ __launch_bounds__(320, 1)
void tag_kernel(const float* __restrict__ hs, const float* __restrict__ Wtag,
                const float* __restrict__ btag, const int* __restrict__ maskp,
                int* __restrict__ out, int c0, int CH)
{
    __shared__ float ht[16][132];
    __shared__ float lg[16][20];
    const int tid = threadIdx.x;
    const int bpg = CH >> 4;
    const int b = blockIdx.x / bpg;
    const int tg = blockIdx.x % bpg;
    const int lt0 = tg * 16;

    for (int idx = tid; idx < 16 * 128; idx += 320)
        ht[idx >> 7][idx & 127] = hs[((long)b * CH + lt0 + (idx >> 7)) * HH + (idx & 127)];
    __syncthreads();

    {
        int tl = tid / 20, l = tid - tl * 20;
        float a = btag[l];
        const float* w0 = Wtag + (long)l * 256;
#pragma unroll
        for (int r = 0; r < 128; ++r) a += (w0[r] + w0[r + 128]) * ht[tl][r];
        lg[tl][l] = a;
    }
    __syncthreads();
    if (tid < 16) {
        float best = lg[tid][0];
        int bi = 0;
#pragma unroll
        for (int l = 1; l < NL; ++l) {
            float v = lg[tid][l];
            if (v > best) { best = v; bi = l; }   // first-max (np.argmax semantics)
        }
        int t = c0 + lt0 + tid;
        out[b * TT + t] = maskp[b * TT + t] * bi;
    }
}

extern "C" void kernel_launch(void* const* d_in, const int* in_sizes, int n_in,
                              void* d_out, int out_size, void* d_ws, size_t ws_size,
                              hipStream_t stream) {
    const int* word_inputs   = (const int*)d_in[0];
    const int* biword_inputs = (const int*)d_in[1];
    const int* gaz_word_ids  = (const int*)d_in[2];
    const int* gaz_starts    = (const int*)d_in[3];
    const int* gaz_mask      = (const int*)d_in[4];
    const int* maskp         = (const int*)d_in[5];
    const float* word_table   = (const float*)d_in[6];
    const float* biword_table = (const float*)d_in[7];
    const float* gaz_table    = (const float*)d_in[8];
    const float* W_ih   = (const float*)d_in[9];
    const float* W_hh   = (const float*)d_in[10];
    const float* b_lstm = (const float*)d_in[11];
    const float* Wa_ih  = (const float*)d_in[12];
    const float* Wa_hh  = (const float*)d_in[13];
    const float* b_alpha= (const float*)d_in[14];
    const float* Ww_ih  = (const float*)d_in[15];
    const float* Ww_hh  = (const float*)d_in[16];
    const float* b_word = (const float*)d_in[17];
    const float* W_tag  = (const float*)d_in[18];
    const float* b_tag  = (const float*)d_in[19];
    int* out = (int*)d_out;
    float* ws = (float*)d_ws;

    // choose T-chunk so workspace fits: bytes = 118784*CH + 143360
    int CH = 16;
    if      (ws_size >= 118784UL * 512 + 143360UL) CH = 512;
    else if (ws_size >= 118784UL * 128 + 143360UL) CH = 128;
    else if (ws_size >= 118784UL *  32 + 143360UL) CH = 32;

    float* g3x = ws;                               // B*CH*384
    float* axb = g3x + 8L * CH * 384;              // B*CH*128
    float* gwT = axb + 8L * CH * 128;              // B*CH*8*384
    float* hsb = gwT + 8L * CH * 3072;             // B*CH*128
    float* stb = hsb + 8L * CH * 128;              // B*4480

    for (int c0 = 0; c0 < TT; c0 += CH) {
        embed_gates_kernel<<<CH, 512, 0, stream>>>(word_inputs, biword_inputs,
                                                   word_table, biword_table,
                                                   W_ih, Wa_ih, b_lstm, b_alpha,
                                                   g3x, axb, c0, CH);
        gaz_gates_kernel<<<CH, 384, 0, stream>>>(gaz_word_ids, gaz_table,
                                                 Ww_ih, b_word, gwT, c0, CH);
        lattice_scan_kernel<<<BB, 256, 0, stream>>>(g3x, axb, gwT, gaz_starts, gaz_mask,
                                                    W_hh, Ww_hh, Wa_hh, hsb, stb, c0, CH);
        tag_kernel<<<CH / 2, 320, 0, stream>>>(hsb, W_tag, b_tag, maskp, out, c0, CH);
    }
}

// Round 5
// 2695.357 us; speedup vs baseline: 2.8223x; 1.3719x over previous
//
#include <hip/hip_runtime.h>
#include <hip/hip_bf16.h>

#define BB 8
#define TT 512
#define KK 8
#define HH 128
#define G3 384
#define DIN 100
#define DG 50
#define NL 20

#if __has_builtin(__builtin_amdgcn_rcpf)
#define RCP_(x) __builtin_amdgcn_rcpf(x)
#else
#define RCP_(x) (1.0f/(x))
#endif

__device__ __forceinline__ float fexp_(float x) { return __expf(x); }
__device__ __forceinline__ float fsig_(float x) { return RCP_(1.0f + __expf(-x)); }
__device__ __forceinline__ float ftanh_(float x) {
    float e = __expf(2.0f * x);          // saturates correctly: inf -> 1, 0 -> -1
    return 1.0f - 2.0f * RCP_(e + 1.0f);
}
// LDS-ordering barrier that does NOT drain vmcnt (prefetches stay in flight)
__device__ __forceinline__ void barrier_() {
    asm volatile("s_waitcnt lgkmcnt(0)\n\ts_barrier" ::: "memory");
}
__device__ __forceinline__ float rdlane_(float v, int l) {
    return __uint_as_float((unsigned)__builtin_amdgcn_readlane((int)__float_as_uint(v), l));
}

// ---------------- kernel 1a: g3x = x @ W_ih^T + b_lstm ; alphax = x @ Wa_ih^T + b_alpha
__global__ __launch_bounds__(512, 1)
void embed_gates_kernel(const int* __restrict__ wid, const int* __restrict__ bwid,
                        const float* __restrict__ wtab, const float* __restrict__ bwtab,
                        const float* __restrict__ Wih, const float* __restrict__ Waih,
                        const float* __restrict__ bl, const float* __restrict__ ba,
                        float* __restrict__ g3x, float* __restrict__ axo,
                        int c0, int CH)
{
    __shared__ float xs[8][104];
    const int tid = threadIdx.x;
    const int bpg = CH >> 3;
    const int b = blockIdx.x / bpg;
    const int tg = blockIdx.x % bpg;
    const int t0 = c0 + tg * 8;

    for (int idx = tid; idx < 800; idx += 512) {
        int tt = idx / 100;
        int c = idx - tt * 100;
        int t = t0 + tt;
        float v;
        if (c < 50) v = wtab[(long)wid[b * TT + t] * 50 + c];
        else        v = bwtab[(long)bwid[b * TT + t] * 50 + (c - 50)];
        xs[tt][c] = v;
    }
    __syncthreads();

    const int row = tid;
    float w[100];
    const float* wr;
    float bias;
    if (row < G3) { wr = Wih + (long)row * DIN; bias = bl[row]; }
    else          { wr = Waih + (long)(row - G3) * DIN; bias = ba[row - G3]; }
    const float4* wr4 = (const float4*)wr;
#pragma unroll
    for (int q = 0; q < 25; ++q) {
        float4 v = wr4[q];
        w[4*q] = v.x; w[4*q+1] = v.y; w[4*q+2] = v.z; w[4*q+3] = v.w;
    }
#pragma unroll 1
    for (int tt = 0; tt < 8; ++tt) {
        float a = bias;
#pragma unroll
        for (int c = 0; c < 100; ++c) a += w[c] * xs[tt][c];
        int lt = t0 - c0 + tt;
        if (row < G3) g3x[((long)b * CH + lt) * G3 + row] = a;
        else          axo[((long)b * CH + lt) * HH + (row - G3)] = a;
    }
}

// ---------------- kernel 1b: gwT[b][t][k][384] = Ww_ih @ gaz_emb + b_word
__global__ __launch_bounds__(384, 1)
void gaz_gates_kernel(const int* __restrict__ gids, const float* __restrict__ gtab,
                      const float* __restrict__ Wwih, const float* __restrict__ bw,
                      float* __restrict__ gwT, int c0, int CH)
{
    __shared__ float ges[64][52];
    const int tid = threadIdx.x;
    const int bpg = CH >> 3;
    const int b = blockIdx.x / bpg;
    const int tg = blockIdx.x % bpg;
    const int t0 = c0 + tg * 8;

    for (int idx = tid; idx < 64 * 50; idx += 384) {
        int p = idx / 50;
        int c = idx - p * 50;
        int tt = p >> 3, k = p & 7;
        int gid = gids[((long)(b * TT + t0 + tt)) * KK + k];
        ges[p][c] = gtab[(long)gid * DG + c];
    }
    __syncthreads();

    const int row = tid;
    float w[50];
    const float2* wr2 = (const float2*)(Wwih + (long)row * DG);
#pragma unroll
    for (int q = 0; q < 25; ++q) { float2 v = wr2[q]; w[2*q] = v.x; w[2*q+1] = v.y; }
    const float bias = bw[row];
    const int lt0 = t0 - c0;
#pragma unroll 1
    for (int p = 0; p < 64; ++p) {
        float a = bias;
#pragma unroll
        for (int c = 0; c < 50; ++c) a += w[c] * ges[p][c];
        int tt = p >> 3, k = p & 7;
        gwT[((long)(b * CH + lt0 + tt) * KK + k) * G3 + row] = a;
    }
}

// ---------------- kernel 2: sequential lattice scan, one block per batch
// 256 threads = 4 waves = 1 wave/SIMD -> up to 512 regs/lane (VGPR+AGPR).
// W2 = [W_hh;Ww_hh] 3 rows/thread (384) + Wa half-row (64) register-resident.
// Broadcast vectors (h, alpha-input) travel via v_readlane -> SGPR FMA operands.
__global__ __launch_bounds__(256, 1)
void lattice_scan_kernel(const float* __restrict__ g3x, const float* __restrict__ axb,
                         const float* __restrict__ gwT, const int* __restrict__ gstarts,
                         const int* __restrict__ gmask,
                         const float* __restrict__ Whh, const float* __restrict__ Wwhh,
                         const float* __restrict__ Wahh,
                         float* __restrict__ hs, float* __restrict__ state,
                         int c0, int CH)
{
    __shared__ float cring[8][132];
    __shared__ float cwS[8][132];
    __shared__ float wwh[8][388];
    __shared__ float whh[G3];
    __shared__ float hcur[HH];
    __shared__ int   vmaskS[8];

    const int t = threadIdx.x;
    const int b = blockIdx.x;
    const int lane = t & 63;
    const int rq = t >> 1, hf = t & 1;       // phase C/D mapping (row, col-half)
    const int kB = t >> 5, l5 = t & 31;      // phase B mapping: k-group, row-quad
    const int rb = l5 << 2;

    // ---- register weight stash (448 floats/thread, VGPR+AGPR)
    float W0[HH], W1[HH], W2r[HH], WAr[64];
    {
        const float4* r0p = (const float4*)(Whh + (long)t * HH);
        const float4* r1p = (t < 128) ? (const float4*)(Whh + (long)(t + 256) * HH)
                                      : (const float4*)(Wwhh + (long)(t - 128) * HH);
        const float4* r2p = (const float4*)(Wwhh + (long)(t + 128) * HH);
#pragma unroll
        for (int q = 0; q < 32; ++q) {
            float4 v0 = r0p[q]; W0[4*q]=v0.x; W0[4*q+1]=v0.y; W0[4*q+2]=v0.z; W0[4*q+3]=v0.w;
            float4 v1 = r1p[q]; W1[4*q]=v1.x; W1[4*q+1]=v1.y; W1[4*q+2]=v1.z; W1[4*q+3]=v1.w;
            float4 v2 = r2p[q]; W2r[4*q]=v2.x; W2r[4*q+1]=v2.y; W2r[4*q+2]=v2.z; W2r[4*q+3]=v2.w;
        }
        const float4* wap = (const float4*)(Wahh + (long)rq * HH + hf * 64);
#pragma unroll
        for (int q = 0; q < 16; ++q) {
            float4 v = wap[q]; WAr[4*q]=v.x; WAr[4*q+1]=v.y; WAr[4*q+2]=v.z; WAr[4*q+3]=v.w;
        }
    }

    float* st = state + (long)b * 4480;  // cring 1024 | wwh 3072 | whh 384
    if (c0 == 0) {
        for (int idx = t; idx < 8 * 132; idx += 256) ((float*)cring)[idx] = 0.f;
        for (int idx = t; idx < 8 * 388; idx += 256) ((float*)wwh)[idx] = 0.f;
        for (int idx = t; idx < G3; idx += 256) whh[idx] = 0.f;
    } else {
        for (int idx = t; idx < 1024; idx += 256) cring[idx >> 7][idx & 127] = st[idx];
        for (int idx = t; idx < 3072; idx += 256) wwh[idx / 384][idx % 384] = st[1024 + idx];
        for (int idx = t; idx < 384; idx += 256) whh[idx] = st[4096 + idx];
    }
    barrier_();

    const long gwstep = (long)KK * G3;        // 3072
    const float* gwB = gwT + (long)b * CH * gwstep + (long)kB * G3;
    const long g3base = (long)b * CH * G3;
    const long axbase = (long)b * CH * HH;

    // ---- prefetch (step c0)
    float4 pA = *(const float4*)(gwB + rb);
    float4 pF = *(const float4*)(gwB + rb + 128);
    float4 pG = *(const float4*)(gwB + rb + 256);
    int rs = gstarts[(b * TT + c0) * KK + kB];
    int rm = gmask  [(b * TT + c0) * KK + kB];
    float pg0 = g3x[g3base + rq];
    float pg1 = g3x[g3base + rq + 128];
    float pg2 = g3x[g3base + rq + 256];
    float pax = axb[axbase + rq];

    for (int j = c0; j < c0 + CH; ++j) {
        const int lt = j - c0;
        const bool valid = (rm != 0);
        const int slot = rs & 7;
        const float4 cA = pA, cF = pF, cG = pG;
        const float dg0 = pg0, dg1 = pg1, dg2 = pg2, dax = pax;

        if (l5 == 0) vmaskS[kB] = valid ? 1 : 0;

        // prefetch next step (loads stay in flight across raw barriers)
        if (lt + 1 < CH) {
            const float* gw = gwB + (long)(lt + 1) * gwstep;
            pA = *(const float4*)(gw + rb);
            pF = *(const float4*)(gw + rb + 128);
            pG = *(const float4*)(gw + rb + 256);
            rs = gstarts[(b * TT + j + 1) * KK + kB];
            rm = gmask  [(b * TT + j + 1) * KK + kB];
            pg0 = g3x[g3base + (long)(lt + 1) * G3 + rq];
            pg1 = g3x[g3base + (long)(lt + 1) * G3 + rq + 128];
            pg2 = g3x[g3base + (long)(lt + 1) * G3 + rq + 256];
            pax = axb[axbase + (long)(lt + 1) * HH + rq];
        }

        // ---- Phase B: word-LSTM cells; 32 lanes x 4 consecutive rows per k
        {
            float4 wi = *(const float4*)&wwh[slot][rb];
            float4 wf = *(const float4*)&wwh[slot][rb + 128];
            float4 wg = *(const float4*)&wwh[slot][rb + 256];
            float4 cs = *(const float4*)&cring[slot][rb];
            float4 cw;
            cw.x = fsig_(cF.x + wf.x) * cs.x + fsig_(cA.x + wi.x) * ftanh_(cG.x + wg.x);
            cw.y = fsig_(cF.y + wf.y) * cs.y + fsig_(cA.y + wi.y) * ftanh_(cG.y + wg.y);
            cw.z = fsig_(cF.z + wf.z) * cs.z + fsig_(cA.z + wi.z) * ftanh_(cG.z + wg.z);
            cw.w = fsig_(cF.w + wf.w) * cs.w + fsig_(cA.w + wi.w) * ftanh_(cG.w + wg.w);
            *(float4*)&cwS[kB][rb] = cw;
        }
        barrier_();

        // block-wide valid mask (wave-uniform)
        const int4 vm0 = *(const int4*)&vmaskS[0];
        const int4 vm1 = *(const int4*)&vmaskS[4];
        const unsigned mask8 = (vm0.x ? 1u : 0) | (vm0.y ? 2u : 0) | (vm0.z ? 4u : 0) | (vm0.w ? 8u : 0)
                             | (vm1.x ? 16u : 0) | (vm1.y ? 32u : 0) | (vm1.z ? 64u : 0) | (vm1.w ? 128u : 0);
        const bool hw_any = (mask8 != 0u);

        // ---- Phase C: alpha aggregation; thread owns (row rq, col-half hf)
        float sumw = 0.f, sumwc = 0.f;
#pragma unroll
        for (int k = 0; k < 8; ++k) {
            if (mask8 & (1u << k)) {
                const float4* cp = (const float4*)&cwS[k][hf * 64];
                float a0 = 0.f, a1 = 0.f, a2 = 0.f, a3 = 0.f;
#pragma unroll
                for (int q = 0; q < 16; q += 4) {
                    float4 c0v = cp[q], c1v = cp[q+1], c2v = cp[q+2], c3v = cp[q+3];
                    a0 += WAr[4*q]*c0v.x + WAr[4*q+1]*c0v.y + WAr[4*q+2]*c0v.z + WAr[4*q+3]*c0v.w;
                    a1 += WAr[4*q+4]*c1v.x + WAr[4*q+5]*c1v.y + WAr[4*q+6]*c1v.z + WAr[4*q+7]*c1v.w;
                    a2 += WAr[4*q+8]*c2v.x + WAr[4*q+9]*c2v.y + WAr[4*q+10]*c2v.z + WAr[4*q+11]*c2v.w;
                    a3 += WAr[4*q+12]*c3v.x + WAr[4*q+13]*c3v.y + WAr[4*q+14]*c3v.z + WAr[4*q+15]*c3v.w;
                }
                float acc = (a0 + a1) + (a2 + a3);
                acc += __shfl_xor(acc, 1);     // combine col-halves (pair in same wave)
                float a = fsig_(dax + acc);
                float w = fexp_(a);
                sumw += w;
                sumwc += w * cwS[k][rq];
            }
        }

        // ---- Phase D: char cell + merge (both pair-lanes compute, hf==0 writes)
        float i_ = fsig_(dg0 + whh[rq]);
        float o_ = fsig_(dg1 + whh[rq + 128]);
        float g_ = ftanh_(dg2 + whh[rq + 256]);
        float cprev = cring[(j - 1) & 7][rq];
        float wc = fexp_(i_);
        float csoft = (wc * g_ + sumwc) / (wc + sumw);
        float ccpl = (1.f - i_) * cprev + i_ * g_;
        float cn = hw_any ? csoft : ccpl;
        float hn = o_ * ftanh_(cn);
        if (hf == 0) {
            cring[j & 7][rq] = cn;
            hcur[rq] = hn;
            hs[((long)b * CH + lt) * HH + rq] = hn;
        }
        barrier_();

        // ---- Phase E: W2 @ h via readlane->SGPR broadcast; weights stay in regs
        float2 hv = *(const float2*)&hcur[lane << 1];   // lane L holds h[2L],h[2L+1]
        float a0 = 0.f, b0 = 0.f, a1 = 0.f, b1 = 0.f, a2 = 0.f, b2 = 0.f;
#pragma unroll
        for (int m = 0; m < 64; ++m) {
            float sx = rdlane_(hv.x, m);    // h[2m]  (SGPR)
            float sy = rdlane_(hv.y, m);    // h[2m+1] (SGPR)
            a0 = fmaf(sx, W0[2*m], a0);   b0 = fmaf(sy, W0[2*m+1], b0);
            a1 = fmaf(sx, W1[2*m], a1);   b1 = fmaf(sy, W1[2*m+1], b1);
            a2 = fmaf(sx, W2r[2*m], a2);  b2 = fmaf(sy, W2r[2*m+1], b2);
        }
        {
            float e0 = a0 + b0, e1 = a1 + b1, e2 = a2 + b2;
            whh[t] = e0;                                   // W_hh rows 0..255
            if (t < 128) whh[t + 256] = e1;                // W_hh rows 256..383
            else         wwh[j & 7][t - 128] = e1;         // Ww rows 0..127
            wwh[j & 7][t + 128] = e2;                      // Ww rows 128..383
        }
        barrier_();
    }

    // persist state for next chunk
    for (int idx = t; idx < 1024; idx += 256) st[idx] = cring[idx >> 7][idx & 127];
    for (int idx = t; idx < 3072; idx += 256) st[1024 + idx] = wwh[idx / 384][idx % 384];
    for (int idx = t; idx < 384; idx += 256) st[4096 + idx] = whh[idx];
}

// ---------------- kernel 3: logits + argmax (fwd==bwd, so fold W_tag halves)
__global__ __launch_bounds__(320, 1)
void tag_kernel(const float* __restrict__ hs, const float* __restrict__ Wtag,
                const float* __restrict__ btag, const int* __restrict__ maskp,
                int* __restrict__ out, int c0, int CH)
{
    __shared__ float ht[16][132];
    __shared__ float lg[16][20];
    const int tid = threadIdx.x;
    const int bpg = CH >> 4;
    const int b = blockIdx.x / bpg;
    const int tg = blockIdx.x % bpg;
    const int lt0 = tg * 16;

    for (int idx = tid; idx < 16 * 128; idx += 320)
        ht[idx >> 7][idx & 127] = hs[((long)b * CH + lt0 + (idx >> 7)) * HH + (idx & 127)];
    __syncthreads();

    {
        int tl = tid / 20, l = tid - tl * 20;
        float a = btag[l];
        const float* w0 = Wtag + (long)l * 256;
#pragma unroll
        for (int r = 0; r < 128; ++r) a += (w0[r] + w0[r + 128]) * ht[tl][r];
        lg[tl][l] = a;
    }
    __syncthreads();
    if (tid < 16) {
        float best = lg[tid][0];
        int bi = 0;
#pragma unroll
        for (int l = 1; l < NL; ++l) {
            float v = lg[tid][l];
            if (v > best) { best = v; bi = l; }   // first-max (np.argmax semantics)
        }
        int t = c0 + lt0 + tid;
        out[b * TT + t] = maskp[b * TT + t] * bi;
    }
}

extern "C" void kernel_launch(void* const* d_in, const int* in_sizes, int n_in,
                              void* d_out, int out_size, void* d_ws, size_t ws_size,
                              hipStream_t stream) {
    const int* word_inputs   = (const int*)d_in[0];
    const int* biword_inputs = (const int*)d_in[1];
    const int* gaz_word_ids  = (const int*)d_in[2];
    const int* gaz_starts    = (const int*)d_in[3];
    const int* gaz_mask      = (const int*)d_in[4];
    const int* maskp         = (const int*)d_in[5];
    const float* word_table   = (const float*)d_in[6];
    const float* biword_table = (const float*)d_in[7];
    const float* gaz_table    = (const float*)d_in[8];
    const float* W_ih   = (const float*)d_in[9];
    const float* W_hh   = (const float*)d_in[10];
    const float* b_lstm = (const float*)d_in[11];
    const float* Wa_ih  = (const float*)d_in[12];
    const float* Wa_hh  = (const float*)d_in[13];
    const float* b_alpha= (const float*)d_in[14];
    const float* Ww_ih  = (const float*)d_in[15];
    const float* Ww_hh  = (const float*)d_in[16];
    const float* b_word = (const float*)d_in[17];
    const float* W_tag  = (const float*)d_in[18];
    const float* b_tag  = (const float*)d_in[19];
    int* out = (int*)d_out;
    float* ws = (float*)d_ws;

    // choose T-chunk so workspace fits: bytes = 118784*CH + 143360
    int CH = 16;
    if      (ws_size >= 118784UL * 512 + 143360UL) CH = 512;
    else if (ws_size >= 118784UL * 128 + 143360UL) CH = 128;
    else if (ws_size >= 118784UL *  32 + 143360UL) CH = 32;

    float* g3x = ws;                               // B*CH*384
    float* axb = g3x + 8L * CH * 384;              // B*CH*128
    float* gwT = axb + 8L * CH * 128;              // B*CH*8*384
    float* hsb = gwT + 8L * CH * 3072;             // B*CH*128
    float* stb = hsb + 8L * CH * 128;              // B*4480

    for (int c0 = 0; c0 < TT; c0 += CH) {
        embed_gates_kernel<<<CH, 512, 0, stream>>>(word_inputs, biword_inputs,
                                                   word_table, biword_table,
                                                   W_ih, Wa_ih, b_lstm, b_alpha,
                                                   g3x, axb, c0, CH);
        gaz_gates_kernel<<<CH, 384, 0, stream>>>(gaz_word_ids, gaz_table,
                                                 Ww_ih, b_word, gwT, c0, CH);
        lattice_scan_kernel<<<BB, 256, 0, stream>>>(g3x, axb, gwT, gaz_starts, gaz_mask,
                                                    W_hh, Ww_hh, Wa_hh, hsb, stb, c0, CH);
        tag_kernel<<<CH / 2, 320, 0, stream>>>(hsb, W_tag, b_tag, maskp, out, c0, CH);
    }
}